// Round 1
// baseline (28.623 us; speedup 1.0000x reference)
//
#include <hip/hip_runtime.h>
#include <math.h>

// Problem geometry (fixed by the reference): probability [64, 2, 512, 512] fp32.
constexpr int B       = 64;
constexpr int HW      = 512 * 512;        // pixels per (batch, channel)
constexpr int CHUNKS  = 32;               // blocks per batch -> 2048 blocks total
constexpr int PIX     = HW / CHUNKS;      // 8192 pixels per block
constexpr int THREADS = 256;

// Kernel 1: per-block partial sums of sigmoid(x1 - x0) = softmax(axis=1)[ch 1].
__global__ __launch_bounds__(THREADS)
void lb_partials(const float* __restrict__ prob, float* __restrict__ partials) {
    const int blk = blockIdx.x;
    const int b   = blk >> 5;             // blk / CHUNKS
    const int c   = blk & (CHUNKS - 1);   // blk % CHUNKS

    const float4* __restrict__ x0 =
        reinterpret_cast<const float4*>(prob + (size_t)b * 2 * HW + (size_t)c * PIX);
    const float4* __restrict__ x1 =
        reinterpret_cast<const float4*>(prob + (size_t)b * 2 * HW + HW + (size_t)c * PIX);

    constexpr int N4 = PIX / 4;           // 2048 float4 per channel per block
    float acc = 0.f;
    for (int i = threadIdx.x; i < N4; i += THREADS) {   // 8 iterations
        float4 a = x0[i];
        float4 d = x1[i];
        acc += 1.f / (1.f + expf(a.x - d.x));
        acc += 1.f / (1.f + expf(a.y - d.y));
        acc += 1.f / (1.f + expf(a.z - d.z));
        acc += 1.f / (1.f + expf(a.w - d.w));
    }

    // wave64 reduction
    #pragma unroll
    for (int off = 32; off > 0; off >>= 1)
        acc += __shfl_down(acc, off, 64);

    __shared__ float sdata[THREADS / 64];
    const int lane = threadIdx.x & 63;
    const int wid  = threadIdx.x >> 6;
    if (lane == 0) sdata[wid] = acc;
    __syncthreads();
    if (threadIdx.x == 0) {
        float s = 0.f;
        #pragma unroll
        for (int w = 0; w < THREADS / 64; ++w) s += sdata[w];
        partials[blk] = s;
    }
}

// Kernel 2: one wave; lane b finishes batch b in double, then the scalar logic.
__global__ __launch_bounds__(64)
void lb_final(const float* __restrict__ partials, float* __restrict__ out) {
    const int b = threadIdx.x;            // 0..63 == batch index
    double s = 0.0;
    #pragma unroll
    for (int c = 0; c < CHUNKS; ++c) s += (double)partials[b * CHUNKS + c];

    const double LOW  = 131050.0;
    const double HIGH = 131100.0;

    // low_vec_sum = sum over the whole batch of (s - LOW)^2
    double dl  = s - LOW;
    double lvs = dl * dl;
    #pragma unroll
    for (int off = 32; off > 0; off >>= 1) lvs += __shfl_xor(lvs, off, 64);

    // Faithful reproduction of the reference's branchy contributions.
    double contrib, count;
    if (s >= HIGH)      { double d = s - HIGH; contrib = d * d; count = 1.0; }
    else if (s <= LOW)  { contrib = lvs;                        count = (double)B; }
    else                { contrib = 0.0;                        count = 1.0; }

    double cs = contrib, cn = count;
    #pragma unroll
    for (int off = 32; off > 0; off >>= 1) {
        cs += __shfl_xor(cs, off, 64);
        cn += __shfl_xor(cn, off, 64);
    }
    if (b == 0) out[0] = (float)(cs / cn);
}

extern "C" void kernel_launch(void* const* d_in, const int* in_sizes, int n_in,
                              void* d_out, int out_size, void* d_ws, size_t ws_size,
                              hipStream_t stream) {
    const float* prob     = (const float*)d_in[0];
    float*       out      = (float*)d_out;
    float*       partials = (float*)d_ws;   // 2048 floats = 8 KB, always written before read

    lb_partials<<<B * CHUNKS, THREADS, 0, stream>>>(prob, partials);
    lb_final<<<1, 64, 0, stream>>>(partials, out);
}